// Round 15
// baseline (180.002 us; speedup 1.0000x reference)
//
#include <hip/hip_runtime.h>
#include <stdint.h>

// FourierBlock: B=32, D=64, N=128, L=192, M=32 modes.
// Round 15 = r11 base + two surgical fixes:
//   k1e: k1d restructured to ONE barrier per phase; Xp-stores of phase nn-1
//        moved INSIDE phase nn's load window (double-buffered XE). Barrier's
//        forced vmcnt(0) drain now happens once per phase, with loads+stores
//        co-resident in flight -> HBM busy through the phase.
//        qB/Fb stride 200->196 u16 (8-way -> 4-way LDS conflict, bonus).
//   k2s: k2i verbatim + XCD-bijective swizzle (x=d&7 -> same-XCD oq-siblings
//        share Xp[n] 256KB slice in L2 instead of refetching via L3).
//   k3:  r11 verbatim (~30us, write-roofline).
// ws: Xp 33.5MB @0, Yp 33.5MB @16777216 u16.

typedef __attribute__((ext_vector_type(8))) short short8;
typedef __attribute__((ext_vector_type(4))) float f32x4;
typedef __attribute__((ext_vector_type(4))) unsigned short u16x4;

__device__ __forceinline__ unsigned short f2bf(float f) {
  union { float fv; uint32_t u; } v; v.fv = f;
  uint32_t u = v.u;
  u += 0x7fffu + ((u >> 16) & 1u);          // round-to-nearest-even
  return (unsigned short)(u >> 16);
}

__device__ __forceinline__ f32x4 zero4() { f32x4 z; z[0]=0.f; z[1]=0.f; z[2]=0.f; z[3]=0.f; return z; }

#define TWO_PI_OVER_L (6.283185307179586f / 192.0f)

// ---------------------------------------------------------------------------
// k1e: DFT, 1-barrier phases + in-window stores. grid 512 = (nq32, bq8, ih2),
// 512 thr. LDS: qB0 [128][196]u16 @0 (50176), qB1 @50176, Fb [64][196] @100352
// (25088), XE0 [64][132] @125440 (16896), XE1 @142336. Total 159232 B.
// Phase nn: issue(nn+1) -> storesPrev(nn-1, XE[~nn&1]) -> MFMA(cur) ->
//           XEwrite(XE[nn&1]) -> drain(->nxt) -> ONE barrier.
// ---------------------------------------------------------------------------
__global__ __launch_bounds__(512, 1)
void k1e_dft(const float* __restrict__ q, unsigned short* __restrict__ Xp) {
  extern __shared__ char smem[];
  unsigned short* qB0 = (unsigned short*)smem;
  unsigned short* qB1 = (unsigned short*)(smem + 50176);
  unsigned short* Fb  = (unsigned short*)(smem + 100352);
  unsigned short* XE0 = (unsigned short*)(smem + 125440);
  unsigned short* XE1 = (unsigned short*)(smem + 142336);
  const int t = threadIdx.x, lane = t & 63, w = t >> 6;
  const int l15 = lane & 15, g = lane >> 4;
  const int bid = blockIdx.x;
  const int ih = bid & 1, bq = (bid >> 1) & 7, nq = bid >> 4;
  const int b0 = bq * 4;

  // stage decode + prologue load issue FIRST (latency hides under sincos)
  int srow[12], sqd[12];
#pragma unroll
  for (int j = 0; j < 12; ++j) {
    int fq = (w * 12 + j) * 64 + lane;
    srow[j] = fq / 48;
    sqd[j] = fq - srow[j] * 48;
  }
  size_t qoff[12];
#pragma unroll
  for (int j = 0; j < 12; ++j) {
    int row = srow[j];
    int b = b0 + (row >> 5), i = ih * 32 + (row & 31);
    qoff[j] = ((size_t)((b * 64 + i) * 128)) * 192 + sqd[j] * 4;  // + n*192
  }
  float4 stg[12];
  {
    const int n0 = nq * 4;
#pragma unroll
    for (int j = 0; j < 12; ++j)
      stg[j] = *(const float4*)(q + qoff[j] + (size_t)n0 * 192);
  }

  // DFT basis (VALU-heavy; overlaps prologue loads)
  for (int idx = t; idx < 64 * 192; idx += 512) {
    int cat = idx / 192, l = idx - cat * 192;
    int m = cat >> 1;
    int r = (m * l) % 192;
    float ang = (float)r * TWO_PI_OVER_L;
    float v = (cat & 1) ? -__sinf(ang) : __cosf(ang);
    Fb[cat * 196 + l] = f2bf(v);
  }

#pragma unroll
  for (int j = 0; j < 12; ++j) {
    u16x4 h; h[0] = f2bf(stg[j].x); h[1] = f2bf(stg[j].y);
    h[2] = f2bf(stg[j].z); h[3] = f2bf(stg[j].w);
    *(u16x4*)(qB0 + srow[j] * 196 + sqd[j] * 4) = h;
  }
  __syncthreads();

  for (int nn = 0; nn < 4; ++nn) {
    const int n = nq * 4 + nn;
    unsigned short* cur = (nn & 1) ? qB1 : qB0;
    unsigned short* nxt = (nn & 1) ? qB0 : qB1;
    unsigned short* XEc = (nn & 1) ? XE1 : XE0;
    unsigned short* XEp = (nn & 1) ? XE0 : XE1;

    // (1) issue next phase's loads (stay in flight through the whole phase)
    if (nn < 3) {
#pragma unroll
      for (int j = 0; j < 12; ++j)
        stg[j] = *(const float4*)(q + qoff[j] + (size_t)(n + 1) * 192);
    }

    // (2) stores of the PREVIOUS phase's result (HBM-busy window)
    if (nn > 0) {
      const int np = n - 1;
#pragma unroll
      for (int cc2 = 0; cc2 < 2; ++cc2) {
        int ch = cc2 * 512 + t;
        int m = ch >> 5, c = (ch >> 4) & 1, g2 = (ch >> 2) & 3, dl = ch & 3;
        short8 v = *(const short8*)(XEp + (2 * m + c) * 132 + dl * 32 + g2 * 8);
        int lanep = g2 * 16 + (b0 & 15) + dl;
        int off = np * 131072 + ((((m * 2 + c) * 2 + ih) * 2 + (b0 >> 4)) * 64 + lanep) * 8;
        *(short8*)(Xp + off) = v;
      }
    }

    // (3) MFMA from cur
    f32x4 acc[4];
#pragma unroll
    for (int a = 0; a < 4; ++a) acc[a] = zero4();
    const int row = w * 16 + l15;
#pragma unroll
    for (int kc = 0; kc < 6; ++kc) {
      short8 A = *(const short8*)(cur + row * 196 + kc * 32 + g * 8);
#pragma unroll
      for (int nt = 0; nt < 4; ++nt) {
        short8 Bf = *(const short8*)(Fb + (nt * 16 + l15) * 196 + kc * 32 + g * 8);
        acc[nt] = __builtin_amdgcn_mfma_f32_16x16x32_bf16(A, Bf, acc[nt], 0, 0, 0);
      }
    }

    // (4) C-frags -> XEc (this phase's buffer)
    const int b_loc = w >> 1, i_base = (w & 1) * 16 + g * 4;
#pragma unroll
    for (int nt = 0; nt < 4; ++nt) {
      int cat = nt * 16 + l15;
      f32x4 v = acc[nt];
#pragma unroll
      for (int r = 0; r < 4; ++r)
        XEc[cat * 132 + b_loc * 32 + i_base + r] = f2bf(v[r]);
    }

    // (5) drain loads -> nxt buffer
    if (nn < 3) {
#pragma unroll
      for (int j = 0; j < 12; ++j) {
        u16x4 h; h[0] = f2bf(stg[j].x); h[1] = f2bf(stg[j].y);
        h[2] = f2bf(stg[j].z); h[3] = f2bf(stg[j].w);
        *(u16x4*)(nxt + srow[j] * 196 + sqd[j] * 4) = h;
      }
    }

    // (6) the ONE barrier: nxt ready, XEc complete, XEp fully consumed
    __syncthreads();
  }

  // tail: store phase nn=3's XE (XE[3&1] = XE1)
  {
    const int np = nq * 4 + 3;
#pragma unroll
    for (int cc2 = 0; cc2 < 2; ++cc2) {
      int ch = cc2 * 512 + t;
      int m = ch >> 5, c = (ch >> 4) & 1, g2 = (ch >> 2) & 3, dl = ch & 3;
      short8 v = *(const short8*)(XE1 + (2 * m + c) * 132 + dl * 32 + g2 * 8);
      int lanep = g2 * 16 + (b0 & 15) + dl;
      int off = np * 131072 + ((((m * 2 + c) * 2 + ih) * 2 + (b0 >> 4)) * 64 + lanep) * 8;
      *(short8*)(Xp + off) = v;
    }
  }
}

// ---------------------------------------------------------------------------
// k2s: fused W-stage + complex mix (k2i body verbatim) + XCD-bijective
// swizzle: x=d&7 (XCD), oq=(d>>3)&3, n=x*16+(d>>5) -- the 4 oq-siblings of
// each n are co-resident on one XCD -> Xp[n] slice L2-shared.
// grid 512, 512 thr, LDS 139776 B.
// ---------------------------------------------------------------------------
#define K2_OSTRIDE 34
#define K2_ISTRIDE 546        // 16*34 + 2
#define K2_CSTRIDE 34944      // 64*546
__global__ __launch_bounds__(512, 2)
void k2s_mix(const float* __restrict__ wr, const float* __restrict__ wi,
             const unsigned short* __restrict__ Xp, unsigned short* __restrict__ Yp) {
  extern __shared__ char smem[];
  unsigned short* T = (unsigned short*)smem;
  const int t = threadIdx.x, lane = t & 63, w = t >> 6;
  const int d = blockIdx.x;
  const int n = (d & 7) * 16 + (d >> 5), oq = (d >> 3) & 3;
  const int ol = lane & 15, il0 = (lane >> 4) * 8;

#pragma unroll
  for (int j = 0; j < 32; ++j) {
    int f = j * 512 + t;
    int mg = f & 7, o = (f >> 3) & 15, i = (f >> 7) & 63, c = (f >> 13) & 1;
    const float* src = (c ? wi : wr) + ((n * 64 + i) * 64 + oq * 16 + o) * 32 + mg * 4;
    float4 v = *(const float4*)src;
    u16x4 h; h[0] = f2bf(v.x); h[1] = f2bf(v.y); h[2] = f2bf(v.z); h[3] = f2bf(v.w);
    *(u16x4*)(T + c * K2_CSTRIDE + i * K2_ISTRIDE + o * K2_OSTRIDE + mg * 4) = h;
  }
  __syncthreads();

  unsigned short* yblk = Yp + (n * 4 + oq) * 32768;   // block-private 64KB

#pragma unroll
  for (int mm = 0; mm < 4; ++mm) {
    int m = w * 4 + mm;
    f32x4 acc[2][2];  // [cc][Mt]
#pragma unroll
    for (int a = 0; a < 2; ++a)
#pragma unroll
      for (int b2 = 0; b2 < 2; ++b2) acc[a][b2] = zero4();

#pragma unroll
    for (int ic = 0; ic < 2; ++ic) {
      const unsigned short* xb = Xp + n * 131072 + m * 4096 + ic * 1024 + lane * 8;
      short8 Ar0 = *(const short8*)(xb);
      short8 Ar1 = *(const short8*)(xb + 512);
      short8 Ai0 = *(const short8*)(xb + 2048);
      short8 Ai1 = *(const short8*)(xb + 2048 + 512);

      const unsigned short* tb = T + (ic * 32 + il0) * K2_ISTRIDE + ol * K2_OSTRIDE + m;
      short8 Br, Bi, nBi;
#pragma unroll
      for (int e = 0; e < 8; ++e) {
        Br[e] = (short)tb[e * K2_ISTRIDE];
        Bi[e] = (short)tb[K2_CSTRIDE + e * K2_ISTRIDE];
        nBi[e] = Bi[e] ^ (short)0x8000;   // -Wi
      }

      acc[0][0] = __builtin_amdgcn_mfma_f32_16x16x32_bf16(Ar0, Br,  acc[0][0], 0, 0, 0);
      acc[0][0] = __builtin_amdgcn_mfma_f32_16x16x32_bf16(Ai0, nBi, acc[0][0], 0, 0, 0);
      acc[0][1] = __builtin_amdgcn_mfma_f32_16x16x32_bf16(Ar1, Br,  acc[0][1], 0, 0, 0);
      acc[0][1] = __builtin_amdgcn_mfma_f32_16x16x32_bf16(Ai1, nBi, acc[0][1], 0, 0, 0);
      acc[1][0] = __builtin_amdgcn_mfma_f32_16x16x32_bf16(Ar0, Bi,  acc[1][0], 0, 0, 0);
      acc[1][0] = __builtin_amdgcn_mfma_f32_16x16x32_bf16(Ai0, Br,  acc[1][0], 0, 0, 0);
      acc[1][1] = __builtin_amdgcn_mfma_f32_16x16x32_bf16(Ar1, Bi,  acc[1][1], 0, 0, 0);
      acc[1][1] = __builtin_amdgcn_mfma_f32_16x16x32_bf16(Ai1, Br,  acc[1][1], 0, 0, 0);
    }

    // epilogue: Yp[n][oq][b][2m+cc][ol] -- 64B line per cat pair, one wave
    const int g = lane >> 4;
#pragma unroll
    for (int Mt = 0; Mt < 2; ++Mt)
#pragma unroll
      for (int r = 0; r < 4; ++r) {
        int b = Mt * 16 + g * 4 + r;
        unsigned short* yb = yblk + b * 1024 + (2 * m) * 16 + ol;
        yb[0]  = f2bf(acc[0][Mt][r]);      // cat = 2m
        yb[16] = f2bf(acc[1][Mt][r]);      // cat = 2m+1 (same 64B line)
      }
  }
}

// ---------------------------------------------------------------------------
// K3: iDFT + transposed store (r11 VERBATIM). grid 4096 = (b 32, n 128).
// ---------------------------------------------------------------------------
__global__ __launch_bounds__(256, 4)
void k3_idft(const unsigned short* __restrict__ Yp, float* __restrict__ out) {
  extern __shared__ char smem[];
  unsigned short* Yl = (unsigned short*)smem;        // [cat 64][66]
  float* ol = (float*)(smem + 8448);
  const int t = threadIdx.x, lane = t & 63, w = t >> 6;
  const int n = blockIdx.x & 127, b = blockIdx.x >> 7;

  const unsigned short* ysrc = Yp + (n * 4 * 32 + b) * 1024;   // + oq*32768
#pragma unroll
  for (int j = 0; j < 2; ++j) {
    int f = j * 256 + t;
    int og = f & 1, cat = (f >> 1) & 63, oq = f >> 7;
    short8 v = *(const short8*)(ysrc + oq * 32768 + cat * 16 + og * 8);
    unsigned int* d = (unsigned int*)(Yl + cat * 66 + oq * 16 + og * 8);
    union { short8 s; unsigned int u[4]; } uu; uu.s = v;
    d[0] = uu.u[0]; d[1] = uu.u[1]; d[2] = uu.u[2]; d[3] = uu.u[3];
  }

  short8 Af[3][2];
#pragma unroll
  for (int jm = 0; jm < 3; ++jm) {
    int Mt = w + 4 * jm;
    int lt = Mt * 16 + (lane & 15);
#pragma unroll
    for (int kc = 0; kc < 2; ++kc) {
#pragma unroll
      for (int e = 0; e < 8; ++e) {
        int cat = kc * 32 + (lane >> 4) * 8 + e;
        int m = cat >> 1;
        int r = (m * lt) % 192;
        float ang = (float)r * TWO_PI_OVER_L;
        float coef = (m == 0) ? (1.0f / 192.0f) : (2.0f / 192.0f);
        float v = ((cat & 1) ? -__sinf(ang) : __cosf(ang)) * coef;
        Af[jm][kc][e] = (short)f2bf(v);
      }
    }
  }
  __syncthreads();

  f32x4 acc[3][4];
#pragma unroll
  for (int a = 0; a < 3; ++a)
#pragma unroll
    for (int bq = 0; bq < 4; ++bq) acc[a][bq] = zero4();

#pragma unroll
  for (int kc = 0; kc < 2; ++kc) {
    short8 Bf[4];
#pragma unroll
    for (int nt = 0; nt < 4; ++nt)
#pragma unroll
      for (int e = 0; e < 8; ++e) {
        int cat = kc * 32 + (lane >> 4) * 8 + e;
        Bf[nt][e] = (short)Yl[cat * 66 + nt * 16 + (lane & 15)];
      }
#pragma unroll
    for (int jm = 0; jm < 3; ++jm)
#pragma unroll
      for (int nt = 0; nt < 4; ++nt)
        acc[jm][nt] = __builtin_amdgcn_mfma_f32_16x16x32_bf16(Af[jm][kc], Bf[nt], acc[jm][nt], 0, 0, 0);
  }

#pragma unroll
  for (int jm = 0; jm < 3; ++jm) {
    int Mt = w + 4 * jm;
    int l0 = Mt * 16 + (lane >> 4) * 4;
#pragma unroll
    for (int nt = 0; nt < 4; ++nt) {
      int o = nt * 16 + (lane & 15);
      int lp = l0 ^ ((o & 7) << 2);
      *(f32x4*)(ol + o * 192 + lp) = acc[jm][nt];
    }
  }
  __syncthreads();

  float* dst = out + (b * 64 * 128 + n) * 192;
#pragma unroll
  for (int j = 0; j < 12; ++j) {
    int f = j * 256 + t;
    int o = f / 48, g2 = f - o * 48;
    int lp = g2 * 4;
    int l = lp ^ ((o & 7) << 2);
    f32x4 v = *(const f32x4*)(ol + o * 192 + lp);
    *(f32x4*)(dst + o * (128 * 192) + l) = v;
  }
}

// ---------------------------------------------------------------------------
extern "C" void kernel_launch(void* const* d_in, const int* in_sizes, int n_in,
                              void* d_out, int out_size, void* d_ws, size_t ws_size,
                              hipStream_t stream) {
  const float* q  = (const float*)d_in[0];
  const float* wr = (const float*)d_in[1];
  const float* wi = (const float*)d_in[2];
  float* out = (float*)d_out;

  unsigned short* Xp = (unsigned short*)d_ws;            // 33.5 MB
  unsigned short* Yp = Xp + 16777216;                    // 33.5 MB

  hipFuncSetAttribute((const void*)k1e_dft, hipFuncAttributeMaxDynamicSharedMemorySize, 159232);
  hipFuncSetAttribute((const void*)k2s_mix, hipFuncAttributeMaxDynamicSharedMemorySize, 139776);
  hipFuncSetAttribute((const void*)k3_idft, hipFuncAttributeMaxDynamicSharedMemorySize, 57600);

  k1e_dft<<<dim3(512), dim3(512), 159232, stream>>>(q, Xp);
  k2s_mix<<<dim3(512), dim3(512), 139776, stream>>>(wr, wi, Xp, Yp);
  k3_idft<<<dim3(4096), dim3(256), 57600, stream>>>(Yp, out);
}